// Round 1
// baseline (806.004 us; speedup 1.0000x reference)
//
#include <hip/hip_runtime.h>

// Problem constants (match reference setup_inputs / CUTOFF / N_IMAGES)
constexpr int M = 8;
constexpr int N = 400;
constexpr int K = 27;               // (2*N_IMAGES+1)^3
constexpr float CUT2 = 36.0f;       // CUTOFF^2
constexpr int D  = M * K * N * N;   // 34,560,000 elements per [M,K,N,N] output
constexpr int F4 = D / 4;           // 8,640,000 float4 units per such region

typedef float f32x4 __attribute__((ext_vector_type(4)));

// ws layout (all 16B-aligned):
//   wrapped : float4[M*N]  (x,y,z,pad) at byte 0       (51200 B)
//   wo      : int4  [M*N]  (x,y,z,pad) at byte 51200   (51200 B)
//   shift   : float4[M*K]  (x,y,z,pad) at byte 102400  ( 3456 B)
constexpr int WS_WRAPPED = 0;
constexpr int WS_WO      = 51200;
constexpr int WS_SHIFT   = 102400;

__global__ __launch_bounds__(128)
void setup_kernel(const float* __restrict__ coords, const float* __restrict__ cell,
                  float4* __restrict__ wrapped, int4* __restrict__ wo,
                  float4* __restrict__ shift)
{
    int m = blockIdx.x;
    const float* c = cell + m * 9;
    float c00 = c[0], c01 = c[1], c02 = c[2];
    float c10 = c[3], c11 = c[4], c12 = c[5];
    float c20 = c[6], c21 = c[7], c22 = c[8];

    // 3x3 inverse via adjugate (cell is well-conditioned here)
    float det = c00 * (c11 * c22 - c12 * c21)
              - c01 * (c10 * c22 - c12 * c20)
              + c02 * (c10 * c21 - c11 * c20);
    float rd = 1.0f / det;
    float i00 = (c11 * c22 - c12 * c21) * rd, i01 = (c02 * c21 - c01 * c22) * rd, i02 = (c01 * c12 - c02 * c11) * rd;
    float i10 = (c12 * c20 - c10 * c22) * rd, i11 = (c00 * c22 - c02 * c20) * rd, i12 = (c02 * c10 - c00 * c12) * rd;
    float i20 = (c10 * c21 - c11 * c20) * rd, i21 = (c01 * c20 - c00 * c21) * rd, i22 = (c00 * c11 - c01 * c10) * rd;

    for (int n = threadIdx.x; n < N; n += blockDim.x) {
        int b = (m * N + n) * 3;
        float x = coords[b + 0], y = coords[b + 1], z = coords[b + 2];
        float p0 = x * i00 + y * i10 + z * i20;
        float p1 = x * i01 + y * i11 + z * i21;
        float p2 = x * i02 + y * i12 + z * i22;
        float f0 = floorf(p0), f1 = floorf(p1), f2 = floorf(p2);
        float4 wv;
        wv.x = x - (f0 * c00 + f1 * c10 + f2 * c20);
        wv.y = y - (f0 * c01 + f1 * c11 + f2 * c21);
        wv.z = z - (f0 * c02 + f1 * c12 + f2 * c22);
        wv.w = 0.0f;
        wrapped[m * N + n] = wv;
        int4 ov;
        ov.x = (int)f0; ov.y = (int)f1; ov.z = (int)f2; ov.w = 0;
        wo[m * N + n] = ov;
    }

    if (threadIdx.x < K) {
        int k = threadIdx.x;
        float fx = (float)(k / 9 - 1);
        float fy = (float)((k / 3) % 3 - 1);
        float fz = (float)(k % 3 - 1);
        float4 sv;
        sv.x = fx * c00 + fy * c10 + fz * c20;
        sv.y = fx * c01 + fy * c11 + fz * c21;
        sv.z = fx * c02 + fy * c12 + fz * c22;
        sv.w = 0.0f;
        shift[m * K + k] = sv;
    }
}

__global__ __launch_bounds__(256)
void pairs_kernel(const float4* __restrict__ wrapped, const int4* __restrict__ wo,
                  const float4* __restrict__ shift, float* __restrict__ out)
{
    // LDS transpose buffer for paircoord, padded to 257 float4s per plane.
    // Transpose is WAVE-LOCAL (each wave only exchanges within its own 64
    // tid slots) -> no __syncthreads anywhere -> no s_waitcnt vmcnt(0)
    // drain before a barrier; NT stores stream without blocking.
    __shared__ f32x4 lds[3][257];

    int tid = threadIdx.x;
    int t = blockIdx.x * 256 + tid;           // [0, M*K*N*(N/4)) = [0, 8,640,000)
    int jq = t % (N / 4);                     // j-quad within row
    int r  = t / (N / 4);                     // row = (m*K + k)*N + i
    int i  = r % N;
    int mk = r / N;
    int k  = mk % K;
    int m  = mk / K;
    int j0 = 4 * jq;

    const float4* wrow = wrapped + m * N;
    const int4*   orow = wo      + m * N;

    // 4 consecutive j atoms + row i: all 16B-aligned dwordx4 loads
    float4 wj[4];
    int4   oj[4];
    #pragma unroll
    for (int dj = 0; dj < 4; ++dj) { wj[dj] = wrow[j0 + dj]; oj[dj] = orow[j0 + dj]; }
    float4 wi = wrow[i];
    int4   oi = orow[i];
    float4 sh = shift[mk];
    int imx = k / 9 - 1, imy = (k / 3) % 3 - 1, imz = k % 3 - 1;

    float dist[4], msk[4], offv[4], pc[12];
    #pragma unroll
    for (int dj = 0; dj < 4; ++dj) {
        // p = (wi - wj) + s, d2 = px*px + py*py + pz*pz  -- no FMA contraction,
        // matches numpy reference association for exact mask agreement at d2==36
        float px = __fadd_rn(__fsub_rn(wi.x, wj[dj].x), sh.x);
        float py = __fadd_rn(__fsub_rn(wi.y, wj[dj].y), sh.y);
        float pz = __fadd_rn(__fsub_rn(wi.z, wj[dj].z), sh.z);
        float d2 = __fadd_rn(__fadd_rn(__fmul_rn(px, px), __fmul_rn(py, py)),
                             __fmul_rn(pz, pz));
        bool mb = (d2 < CUT2) && !((k == (K / 2)) && (i == j0 + dj));
        dist[dj] = mb ? sqrtf(d2) : 0.0f;
        msk[dj]  = mb ? 1.0f : 0.0f;
        pc[3 * dj + 0] = mb ? px : 0.0f;
        pc[3 * dj + 1] = mb ? py : 0.0f;
        pc[3 * dj + 2] = mb ? pz : 0.0f;
        int ox = imx - (oi.x - oj[dj].x) + 1;
        int oy = imy - (oi.y - oj[dj].y) + 1;
        int oz = imz - (oi.z - oj[dj].z) + 1;
        offv[dj] = (float)(oz + 3 * (oy + 3 * ox));
    }

    // Park paircoord in LDS (write phase: stride-16B per lane, conflict-free)
    f32x4 p0 = { pc[0], pc[1], pc[2],  pc[3]  };
    f32x4 p1 = { pc[4], pc[5], pc[6],  pc[7]  };
    f32x4 p2 = { pc[8], pc[9], pc[10], pc[11] };
    lds[0][tid] = p0;
    lds[1][tid] = p1;
    lds[2][tid] = p2;

    f32x4* out4 = reinterpret_cast<f32x4*>(out);
    f32x4 dv = { dist[0], dist[1], dist[2], dist[3] };
    f32x4 mv = { msk[0],  msk[1],  msk[2],  msk[3]  };
    f32x4 ov = { offv[0], offv[1], offv[2], offv[3] };

    // dist/mask/offset: lane-contiguous, full-line NT stores (issued while
    // the LDS writes land -- nothing ever waits on vmcnt in this kernel)
    __builtin_nontemporal_store(dv, out4 + t);
    __builtin_nontemporal_store(mv, out4 + 4 * F4 + t);
    __builtin_nontemporal_store(ov, out4 + 5 * F4 + t);

    // Wave-local transpose readback. wave_barrier orders the ds_writes above
    // against the ds_reads below (zero-cost compiler fence; LDS pipe is
    // in-order per wave, so no workgroup barrier is needed).
    __builtin_amdgcn_wave_barrier();
    __builtin_amdgcn_sched_barrier(0);

    int w64 = tid & ~63;                       // wave base within block
    int l   = tid & 63;
    int base = F4 + 3 * (blockIdx.x * 256 + w64);
    #pragma unroll
    for (int rr = 0; rr < 3; ++rr) {
        int idx = rr * 64 + l;                 // 0..191, lane-consecutive dest
        int s2  = idx / 3;                     // source lane within this wave
        int q   = idx - 3 * s2;                // source piece
        __builtin_nontemporal_store(lds[q][w64 + s2], out4 + base + idx);
    }
}

extern "C" void kernel_launch(void* const* d_in, const int* in_sizes, int n_in,
                              void* d_out, int out_size, void* d_ws, size_t ws_size,
                              hipStream_t stream) {
    const float* coords = (const float*)d_in[0];   // [M,N,3]
    const float* cell   = (const float*)d_in[1];   // [M,3,3]
    float* out = (float*)d_out;

    char* ws = (char*)d_ws;
    float4* wrapped = (float4*)(ws + WS_WRAPPED);
    int4*   wo      = (int4*)  (ws + WS_WO);
    float4* shift   = (float4*)(ws + WS_SHIFT);

    setup_kernel<<<M, 128, 0, stream>>>(coords, cell, wrapped, wo, shift);

    int total = M * K * N * (N / 4);           // 8,640,000 threads
    int blocks = total / 256;                  // 33,750 exactly
    pairs_kernel<<<blocks, 256, 0, stream>>>(wrapped, wo, shift, out);
}